// Round 1
// baseline (2465.570 us; speedup 1.0000x reference)
//
#include <hip/hip_runtime.h>
#include <hip/hip_bf16.h>
#include <math.h>

#define M_TOK 512
#define HD    2048
#define NE    8
#define ID    5632

#define TM 32
#define TN 64
#define BK 32

// ---------------------------------------------------------------- router ----
// One 64-lane wave per token: 8 logits, top-2 (jax tie semantics: earliest
// index wins), renormalized softmax weights, atomic compaction per expert.
__global__ void router_kernel(const float* __restrict__ x,
                              const float* __restrict__ wg,
                              int* __restrict__ counts,
                              int* __restrict__ tok_idx,
                              int* __restrict__ tok_k,
                              float* __restrict__ tok_w) {
    const int m = blockIdx.x;
    const int lane = threadIdx.x;  // 64
    float acc[NE];
#pragma unroll
    for (int e = 0; e < NE; ++e) acc[e] = 0.f;
    const float* xr = x + (size_t)m * HD;
    for (int h = lane; h < HD; h += 64) {
        const float xv = xr[h];
        const float* wr = wg + (size_t)h * NE;
#pragma unroll
        for (int e = 0; e < NE; ++e) acc[e] += xv * wr[e];
    }
#pragma unroll
    for (int e = 0; e < NE; ++e) {
        float v = acc[e];
#pragma unroll
        for (int off = 32; off > 0; off >>= 1) v += __shfl_down(v, off);
        acc[e] = v;
    }
    if (lane == 0) {
        int a = 0;
#pragma unroll
        for (int e = 1; e < NE; ++e) if (acc[e] > acc[a]) a = e;
        int b = (a == 0) ? 1 : 0;
#pragma unroll
        for (int e = 0; e < NE; ++e) {
            if (e == a) continue;
            if (acc[e] > acc[b]) b = e;
        }
        // renormalized top-2 softmax weights: p_a/(p_a+p_b) = 1/(1+e^{lb-la})
        const float wa = 1.f / (1.f + expf(acc[b] - acc[a]));
        const float wb = 1.f - wa;
        const int sa = atomicAdd(&counts[a], 1);
        tok_idx[a * M_TOK + sa] = m;
        tok_k[a * M_TOK + sa] = 0;
        tok_w[a * M_TOK + sa] = wa;
        const int sb = atomicAdd(&counts[b], 1);
        tok_idx[b * M_TOK + sb] = m;
        tok_k[b * M_TOK + sb] = 1;
        tok_w[b * M_TOK + sb] = wb;
    }
}

// --------------------------------------------------------- gemm1 + silu ----
// Per expert: h[s, i] = silu(x_e @ w1g) * (x_e @ w1u), stored bf16 at
// hbuf[(token*2 + rank) * ID + i]. Tiles: TM x TN, K over H.
__global__ __launch_bounds__(256)
void gemm1_silu_kernel(const float* __restrict__ x,
                       const float* __restrict__ w1,
                       const int* __restrict__ counts,
                       const int* __restrict__ tok_idx,
                       const int* __restrict__ tok_k,
                       __hip_bfloat16* __restrict__ hbuf) {
    const int e = blockIdx.z;
    const int ne = counts[e];
    const int m0 = blockIdx.y * TM;
    if (m0 >= ne) return;
    const int i0 = blockIdx.x * TN;

    __shared__ float As[BK][TM + 1];
    __shared__ float Bg[BK][TN];
    __shared__ float Bu[BK][TN];
    __shared__ int row_tok[TM];
    __shared__ int row_k[TM];

    const int tid = threadIdx.x;
    if (tid < TM) {
        const int s = m0 + tid;
        if (s < ne) {
            row_tok[tid] = tok_idx[e * M_TOK + s];
            row_k[tid]   = tok_k[e * M_TOK + s];
        } else {
            row_tok[tid] = -1;
            row_k[tid]   = 0;
        }
    }
    __syncthreads();

    const int tx = tid & 15;   // 16 col groups x 4 cols
    const int ty = tid >> 4;   // 16 row groups x 2 rows

    float accg[2][4] = {{0.f}};
    float accu[2][4] = {{0.f}};

    // A staging map: each thread loads 4 contiguous floats of one row
    const int amm = tid >> 3;         // 0..31
    const int akk = (tid & 7) * 4;    // 0..28
    const int atok = row_tok[amm];

    const size_t w1_base = (size_t)e * HD * (2 * ID);

    for (int k0 = 0; k0 < HD; k0 += BK) {
        float4 av = make_float4(0.f, 0.f, 0.f, 0.f);
        if (atok >= 0)
            av = *(const float4*)(x + (size_t)atok * HD + k0 + akk);
        As[akk + 0][amm] = av.x;
        As[akk + 1][amm] = av.y;
        As[akk + 2][amm] = av.z;
        As[akk + 3][amm] = av.w;
#pragma unroll
        for (int r = 0; r < 2; ++r) {
            const int idx = tid + r * 256;      // float4 slot 0..511
            const int kk = idx >> 4;            // 0..31
            const int ii = (idx & 15) * 4;      // 0..60
            const float* bp = w1 + w1_base + (size_t)(k0 + kk) * (2 * ID) + i0 + ii;
            *(float4*)&Bg[kk][ii] = *(const float4*)bp;
            *(float4*)&Bu[kk][ii] = *(const float4*)(bp + ID);
        }
        __syncthreads();
#pragma unroll
        for (int kk = 0; kk < BK; ++kk) {
            const float a0 = As[kk][ty * 2 + 0];
            const float a1 = As[kk][ty * 2 + 1];
            const float* bgp = &Bg[kk][tx * 4];
            const float* bup = &Bu[kk][tx * 4];
#pragma unroll
            for (int c = 0; c < 4; ++c) {
                const float bg = bgp[c];
                const float bu = bup[c];
                accg[0][c] += a0 * bg;
                accg[1][c] += a1 * bg;
                accu[0][c] += a0 * bu;
                accu[1][c] += a1 * bu;
            }
        }
        __syncthreads();
    }

#pragma unroll
    for (int r = 0; r < 2; ++r) {
        const int mm = ty * 2 + r;
        const int s = m0 + mm;
        if (s < ne) {
            const int t = row_tok[mm];
            const int k = row_k[mm];
            __hip_bfloat16* hr = hbuf + (size_t)(t * 2 + k) * ID + i0 + tx * 4;
#pragma unroll
            for (int c = 0; c < 4; ++c) {
                const float g = accg[r][c];
                const float u = accu[r][c];
                const float hv = (g / (1.f + expf(-g))) * u;
                hr[c] = __float2bfloat16(hv);
            }
        }
    }
}

// ----------------------------------------------------------------- gemm2 ----
// Per expert: down[s, :] = h_e[s, :] @ w2[e]; out[t, :] += weight * down.
__global__ __launch_bounds__(256)
void gemm2_kernel(const __hip_bfloat16* __restrict__ hbuf,
                  const float* __restrict__ w2,
                  const int* __restrict__ counts,
                  const int* __restrict__ tok_idx,
                  const int* __restrict__ tok_k,
                  const float* __restrict__ tok_w,
                  float* __restrict__ out) {
    const int e = blockIdx.z;
    const int ne = counts[e];
    const int m0 = blockIdx.y * TM;
    if (m0 >= ne) return;
    const int i0 = blockIdx.x * TN;   // over H

    __shared__ float As[BK][TM + 1];
    __shared__ float Bs[BK][TN];
    __shared__ int   row_tok[TM];
    __shared__ int   row_k[TM];
    __shared__ float row_w[TM];

    const int tid = threadIdx.x;
    if (tid < TM) {
        const int s = m0 + tid;
        if (s < ne) {
            row_tok[tid] = tok_idx[e * M_TOK + s];
            row_k[tid]   = tok_k[e * M_TOK + s];
            row_w[tid]   = tok_w[e * M_TOK + s];
        } else {
            row_tok[tid] = -1;
            row_k[tid]   = 0;
            row_w[tid]   = 0.f;
        }
    }
    __syncthreads();

    const int tx = tid & 15;
    const int ty = tid >> 4;

    float acc[2][4] = {{0.f}};

    const int amm = tid >> 3;
    const int akk = (tid & 7) * 4;
    const int atok = row_tok[amm];
    const size_t arow = (atok >= 0) ? (size_t)(atok * 2 + row_k[amm]) * ID : 0;

    const size_t w2_base = (size_t)e * ID * HD;

    for (int k0 = 0; k0 < ID; k0 += BK) {
        float a0 = 0.f, a1 = 0.f, a2 = 0.f, a3 = 0.f;
        if (atok >= 0) {
            const __hip_bfloat16* ap = hbuf + arow + k0 + akk;
            a0 = __bfloat162float(ap[0]);
            a1 = __bfloat162float(ap[1]);
            a2 = __bfloat162float(ap[2]);
            a3 = __bfloat162float(ap[3]);
        }
        As[akk + 0][amm] = a0;
        As[akk + 1][amm] = a1;
        As[akk + 2][amm] = a2;
        As[akk + 3][amm] = a3;
#pragma unroll
        for (int r = 0; r < 2; ++r) {
            const int idx = tid + r * 256;
            const int kk = idx >> 4;
            const int ii = (idx & 15) * 4;
            *(float4*)&Bs[kk][ii] =
                *(const float4*)(w2 + w2_base + (size_t)(k0 + kk) * HD + i0 + ii);
        }
        __syncthreads();
#pragma unroll
        for (int kk = 0; kk < BK; ++kk) {
            const float va0 = As[kk][ty * 2 + 0];
            const float va1 = As[kk][ty * 2 + 1];
            const float* bp = &Bs[kk][tx * 4];
#pragma unroll
            for (int c = 0; c < 4; ++c) {
                const float b = bp[c];
                acc[0][c] += va0 * b;
                acc[1][c] += va1 * b;
            }
        }
        __syncthreads();
    }

#pragma unroll
    for (int r = 0; r < 2; ++r) {
        const int mm = ty * 2 + r;
        const int s = m0 + mm;
        if (s < ne) {
            const int t = row_tok[mm];
            const float w = row_w[mm];
            float* orow = out + (size_t)t * HD + i0 + tx * 4;
#pragma unroll
            for (int c = 0; c < 4; ++c)
                atomicAdd(&orow[c], w * acc[r][c]);
        }
    }
}

// ---------------------------------------------------------------- launch ----
extern "C" void kernel_launch(void* const* d_in, const int* in_sizes, int n_in,
                              void* d_out, int out_size, void* d_ws, size_t ws_size,
                              hipStream_t stream) {
    const float* x  = (const float*)d_in[0];
    const float* wg = (const float*)d_in[1];
    const float* w1 = (const float*)d_in[2];
    const float* w2 = (const float*)d_in[3];
    float* out = (float*)d_out;

    char* ws = (char*)d_ws;
    int*   counts  = (int*)(ws);                     // 32 B (pad to 64)
    int*   tok_idx = (int*)(ws + 64);                // 8*512*4 = 16 KiB
    int*   tok_k   = (int*)(ws + 64 + 16384);        // 16 KiB
    float* tok_w   = (float*)(ws + 64 + 32768);      // 16 KiB
    __hip_bfloat16* hbuf = (__hip_bfloat16*)(ws + 65536);  // 512*2*5632*2 = 11.5 MB

    hipMemsetAsync(counts, 0, 64, stream);
    hipMemsetAsync(out, 0, (size_t)M_TOK * HD * sizeof(float), stream);

    router_kernel<<<dim3(M_TOK), dim3(64), 0, stream>>>(x, wg, counts, tok_idx, tok_k, tok_w);

    gemm1_silu_kernel<<<dim3(ID / TN, M_TOK / TM, NE), dim3(256), 0, stream>>>(
        x, w1, counts, tok_idx, tok_k, hbuf);

    gemm2_kernel<<<dim3(HD / TN, M_TOK / TM, NE), dim3(256), 0, stream>>>(
        hbuf, w2, counts, tok_idx, tok_k, tok_w, out);
}

// Round 2
// 1396.667 us; speedup vs baseline: 1.7653x; 1.7653x over previous
//
#include <hip/hip_runtime.h>
#include <hip/hip_bf16.h>
#include <math.h>

#define M_TOK 512
#define HD    2048
#define NE    8
#define ID    5632
#define SPLITK 4

typedef __bf16 bf16x8 __attribute__((ext_vector_type(8)));
typedef float  f32x4  __attribute__((ext_vector_type(4)));

// LDS row stride for 32-k tiles: 32 + 8 pad = 40 elems (80 B, multiple of 16 B
// so ds_read_b128 stays aligned; 20-bank row offset -> only 2-way conflicts on
// fragment reads, which are free).
#define KS 40

__device__ __forceinline__ unsigned int f2bf_raw(float f) {
    unsigned int u = __float_as_uint(f);
    return (u + 0x7FFFu + ((u >> 16) & 1u)) >> 16;  // RNE
}
__device__ __forceinline__ unsigned int pack_bf2(float lo, float hi) {
    return (f2bf_raw(hi) << 16) | (f2bf_raw(lo) & 0xFFFFu);
}
__device__ __forceinline__ unsigned short f2bf(float f) {
    return (unsigned short)(f2bf_raw(f) & 0xFFFFu);
}

// ---------------------------------------------------------------- router ----
__global__ void router_kernel(const float* __restrict__ x,
                              const float* __restrict__ wg,
                              int* __restrict__ counts,
                              int* __restrict__ tok_idx,
                              int* __restrict__ tok_k,
                              float* __restrict__ tok_w) {
    const int m = blockIdx.x;
    const int lane = threadIdx.x;  // 64
    float acc[NE];
#pragma unroll
    for (int e = 0; e < NE; ++e) acc[e] = 0.f;
    const float* xr = x + (size_t)m * HD;
    for (int h = lane; h < HD; h += 64) {
        const float xv = xr[h];
        const float* wr = wg + (size_t)h * NE;
#pragma unroll
        for (int e = 0; e < NE; ++e) acc[e] += xv * wr[e];
    }
#pragma unroll
    for (int e = 0; e < NE; ++e) {
        float v = acc[e];
#pragma unroll
        for (int off = 32; off > 0; off >>= 1) v += __shfl_down(v, off);
        acc[e] = v;
    }
    if (lane == 0) {
        int a = 0;
#pragma unroll
        for (int e = 1; e < NE; ++e) if (acc[e] > acc[a]) a = e;
        int b = (a == 0) ? 1 : 0;
#pragma unroll
        for (int e = 0; e < NE; ++e) {
            if (e == a) continue;
            if (acc[e] > acc[b]) b = e;
        }
        const float wa = 1.f / (1.f + expf(acc[b] - acc[a]));
        const float wb = 1.f - wa;
        const int sa = atomicAdd(&counts[a], 1);
        tok_idx[a * M_TOK + sa] = m;
        tok_k[a * M_TOK + sa] = 0;
        tok_w[a * M_TOK + sa] = wa;
        const int sb = atomicAdd(&counts[b], 1);
        tok_idx[b * M_TOK + sb] = m;
        tok_k[b * M_TOK + sb] = 1;
        tok_w[b * M_TOK + sb] = wb;
    }
}

// --------------------------------------------------- gemm1 (MFMA) + silu ----
// Block: 256 thr = 4 waves. Tile: 128 tokens x (64 gate cols + 64 up cols),
// K over H in steps of 32. Wave w owns rows [32w,32w+32), all 128 cols
// (frags j=0..3 gate, j=4..7 up -> silu*mul fuses per-thread).
__global__ __launch_bounds__(256)
void gemm1_mfma(const float* __restrict__ x,
                const float* __restrict__ w1,
                const int* __restrict__ counts,
                const int* __restrict__ tok_idx,
                const int* __restrict__ tok_k,
                unsigned short* __restrict__ hbuf) {
    const int e = blockIdx.z;
    const int ne = counts[e];
    const int m0 = blockIdx.y * 128;
    if (m0 >= ne) return;
    const int i0 = blockIdx.x * 64;

    __shared__ __align__(16) unsigned short As[128 * KS];
    __shared__ __align__(16) unsigned short Bs[128 * KS];
    __shared__ int rtok[128];
    __shared__ int rrk[128];

    const int tid = threadIdx.x;
    if (tid < 128) {
        const int s = m0 + tid;
        if (s < ne) {
            rtok[tid] = tok_idx[e * M_TOK + s];
            rrk[tid]  = tok_k[e * M_TOK + s];
        } else {
            rtok[tid] = -1;
            rrk[tid]  = 0;
        }
    }
    __syncthreads();

    // ---- A staging map: 4 float4 per thread (row = tid>>3 + 32r, col = (tid&7)*4)
    const int acol = (tid & 7) * 4;
    const float* aptr[4];
    bool aok[4];
    int arow[4];
#pragma unroll
    for (int r = 0; r < 4; ++r) {
        arow[r] = (tid >> 3) + 32 * r;
        const int tk = rtok[arow[r]];
        aok[r] = (tk >= 0);
        aptr[r] = x + (size_t)(tk >= 0 ? tk : 0) * HD + acol;
    }

    // ---- B staging map: pair-of-k rows. krow2 = (tid>>4)*2, col4 = (tid&15)*4.
    const int krow2 = (tid >> 4) * 2;
    const int bcol  = (tid & 15) * 4;
    const float* bptr = w1 + (size_t)e * HD * (2 * ID) + (size_t)krow2 * (2 * ID) + i0 + bcol;
    unsigned short* bs_g = &Bs[(bcol) * KS + krow2];
    unsigned short* bs_u = &Bs[(64 + bcol) * KS + krow2];

    const int lane = tid & 63;
    const int wv   = tid >> 6;
    const int quad = lane >> 4;
    const int l15  = lane & 15;

    f32x4 acc[2][8];
#pragma unroll
    for (int f = 0; f < 2; ++f)
#pragma unroll
        for (int j = 0; j < 8; ++j) acc[f][j] = (f32x4){0.f, 0.f, 0.f, 0.f};

    for (int k0 = 0; k0 < HD; k0 += 32) {
        float4 av[4];
#pragma unroll
        for (int r = 0; r < 4; ++r)
            av[r] = aok[r] ? *(const float4*)(aptr[r] + k0)
                           : make_float4(0.f, 0.f, 0.f, 0.f);
        const float* bp = bptr + (size_t)k0 * (2 * ID);
        const float4 g0 = *(const float4*)(bp);
        const float4 g1 = *(const float4*)(bp + 2 * ID);
        const float4 u0 = *(const float4*)(bp + ID);
        const float4 u1 = *(const float4*)(bp + 3 * ID);

        __syncthreads();  // previous iteration's compute done
#pragma unroll
        for (int r = 0; r < 4; ++r) {
            uint2 wv2;
            wv2.x = pack_bf2(av[r].x, av[r].y);
            wv2.y = pack_bf2(av[r].z, av[r].w);
            *(uint2*)&As[arow[r] * KS + acol] = wv2;
        }
        {
            const float gg0[4] = {g0.x, g0.y, g0.z, g0.w};
            const float gg1[4] = {g1.x, g1.y, g1.z, g1.w};
            const float uu0[4] = {u0.x, u0.y, u0.z, u0.w};
            const float uu1[4] = {u1.x, u1.y, u1.z, u1.w};
#pragma unroll
            for (int j = 0; j < 4; ++j) {
                *(unsigned int*)&bs_g[j * KS] = pack_bf2(gg0[j], gg1[j]);
                *(unsigned int*)&bs_u[j * KS] = pack_bf2(uu0[j], uu1[j]);
            }
        }
        __syncthreads();  // staging visible

        bf16x8 af[2];
#pragma unroll
        for (int f = 0; f < 2; ++f)
            af[f] = *(const bf16x8*)&As[(32 * wv + 16 * f + l15) * KS + quad * 8];
#pragma unroll
        for (int j = 0; j < 8; ++j) {
            const bf16x8 bfj = *(const bf16x8*)&Bs[(16 * j + l15) * KS + quad * 8];
#pragma unroll
            for (int f = 0; f < 2; ++f)
                acc[f][j] = __builtin_amdgcn_mfma_f32_16x16x32_bf16(af[f], bfj, acc[f][j], 0, 0, 0);
        }
    }

    // ---- epilogue: h = silu(g)*u, bf16 store
#pragma unroll
    for (int f = 0; f < 2; ++f) {
        const int rbase = 32 * wv + 16 * f + quad * 4;
#pragma unroll
        for (int reg = 0; reg < 4; ++reg) {
            const int row = rbase + reg;
            const int tk = rtok[row];
            if (tk < 0) continue;
            const int rr = rrk[row];
            unsigned short* hp = hbuf + (size_t)(tk * 2 + rr) * ID + i0 + l15;
#pragma unroll
            for (int j = 0; j < 4; ++j) {
                const float g = acc[f][j][reg];
                const float u = acc[f][j + 4][reg];
                const float h = (g / (1.f + expf(-g))) * u;
                hp[16 * j] = f2bf(h);
            }
        }
    }
}

// --------------------------------------------------------- gemm2 (MFMA) ----
// Block: 128 rows (expert slots) x 128 cols of H, K over I/SPLITK per chunk.
// Epilogue: out[tok] += weight * acc  (fp32 atomics).
__global__ __launch_bounds__(256)
void gemm2_mfma(const unsigned short* __restrict__ hbuf,
                const float* __restrict__ w2,
                const int* __restrict__ counts,
                const int* __restrict__ tok_idx,
                const int* __restrict__ tok_k,
                const float* __restrict__ tok_w,
                float* __restrict__ out) {
    const int e  = blockIdx.z & (NE - 1);
    const int kc = blockIdx.z >> 3;
    const int ne = counts[e];
    const int m0 = blockIdx.y * 128;
    if (m0 >= ne) return;
    const int n0 = blockIdx.x * 128;
    const int kbeg = kc * (ID / SPLITK);

    __shared__ __align__(16) unsigned short As[128 * KS];
    __shared__ __align__(16) unsigned short Bs[128 * KS];
    __shared__ int   rtok[128];
    __shared__ int   rrow[128];   // hbuf row = tok*2+rank
    __shared__ float rw[128];

    const int tid = threadIdx.x;
    if (tid < 128) {
        const int s = m0 + tid;
        if (s < ne) {
            const int t = tok_idx[e * M_TOK + s];
            rtok[tid] = t;
            rrow[tid] = t * 2 + tok_k[e * M_TOK + s];
            rw[tid]   = tok_w[e * M_TOK + s];
        } else {
            rtok[tid] = -1;
            rrow[tid] = -1;
            rw[tid]   = 0.f;
        }
    }
    __syncthreads();

    // ---- A staging: bf16 direct. 2 slots/thread: (row, col8) with 8 bf16 each.
    const int col8 = (tid & 3) * 8;
    const int ar0 = tid >> 2;         // 0..63
    const int ar1 = ar0 + 64;         // 64..127
    const bool aok0 = rrow[ar0] >= 0;
    const bool aok1 = rrow[ar1] >= 0;
    const unsigned short* ap0 = hbuf + (size_t)(aok0 ? rrow[ar0] : 0) * ID + col8 + kbeg;
    const unsigned short* ap1 = hbuf + (size_t)(aok1 ? rrow[ar1] : 0) * ID + col8 + kbeg;

    // ---- B staging: krow2 = (tid>>5)*2 and +16, col4 = (tid&31)*4.
    const int krow2 = (tid >> 5) * 2;
    const int bcol  = (tid & 31) * 4;
    const float* bptr = w2 + (size_t)e * ID * HD + (size_t)(kbeg + krow2) * HD + n0 + bcol;
    unsigned short* bsw = &Bs[bcol * KS + krow2];

    const int lane = tid & 63;
    const int wv   = tid >> 6;
    const int quad = lane >> 4;
    const int l15  = lane & 15;

    f32x4 acc[2][8];
#pragma unroll
    for (int f = 0; f < 2; ++f)
#pragma unroll
        for (int j = 0; j < 8; ++j) acc[f][j] = (f32x4){0.f, 0.f, 0.f, 0.f};

    for (int k0 = 0; k0 < ID / SPLITK; k0 += 32) {
        const uint4 a0 = aok0 ? *(const uint4*)(ap0 + k0) : make_uint4(0, 0, 0, 0);
        const uint4 a1 = aok1 ? *(const uint4*)(ap1 + k0) : make_uint4(0, 0, 0, 0);
        const float* bp = bptr + (size_t)k0 * HD;
        const float4 b0  = *(const float4*)(bp);
        const float4 b1  = *(const float4*)(bp + HD);
        const float4 b16 = *(const float4*)(bp + 16 * (size_t)HD);
        const float4 b17 = *(const float4*)(bp + 17 * (size_t)HD);

        __syncthreads();
        *(uint4*)&As[ar0 * KS + col8] = a0;
        *(uint4*)&As[ar1 * KS + col8] = a1;
        {
            const float r0[4]  = {b0.x, b0.y, b0.z, b0.w};
            const float r1[4]  = {b1.x, b1.y, b1.z, b1.w};
            const float r16[4] = {b16.x, b16.y, b16.z, b16.w};
            const float r17[4] = {b17.x, b17.y, b17.z, b17.w};
#pragma unroll
            for (int j = 0; j < 4; ++j) {
                *(unsigned int*)&bsw[j * KS]      = pack_bf2(r0[j], r1[j]);
                *(unsigned int*)&bsw[j * KS + 16] = pack_bf2(r16[j], r17[j]);
            }
        }
        __syncthreads();

        bf16x8 af[2];
#pragma unroll
        for (int f = 0; f < 2; ++f)
            af[f] = *(const bf16x8*)&As[(32 * wv + 16 * f + l15) * KS + quad * 8];
#pragma unroll
        for (int j = 0; j < 8; ++j) {
            const bf16x8 bfj = *(const bf16x8*)&Bs[(16 * j + l15) * KS + quad * 8];
#pragma unroll
            for (int f = 0; f < 2; ++f)
                acc[f][j] = __builtin_amdgcn_mfma_f32_16x16x32_bf16(af[f], bfj, acc[f][j], 0, 0, 0);
        }
    }

    // ---- epilogue: weighted atomic accumulate into out
#pragma unroll
    for (int f = 0; f < 2; ++f) {
        const int rbase = 32 * wv + 16 * f + quad * 4;
#pragma unroll
        for (int reg = 0; reg < 4; ++reg) {
            const int row = rbase + reg;
            const int t = rtok[row];
            if (t < 0) continue;
            const float w = rw[row];
            float* op = out + (size_t)t * HD + n0 + l15;
#pragma unroll
            for (int j = 0; j < 8; ++j)
                atomicAdd(op + 16 * j, w * acc[f][j][reg]);
        }
    }
}

// ---------------------------------------------------------------- launch ----
extern "C" void kernel_launch(void* const* d_in, const int* in_sizes, int n_in,
                              void* d_out, int out_size, void* d_ws, size_t ws_size,
                              hipStream_t stream) {
    const float* x  = (const float*)d_in[0];
    const float* wg = (const float*)d_in[1];
    const float* w1 = (const float*)d_in[2];
    const float* w2 = (const float*)d_in[3];
    float* out = (float*)d_out;

    char* ws = (char*)d_ws;
    int*   counts  = (int*)(ws);
    int*   tok_idx = (int*)(ws + 64);
    int*   tok_k   = (int*)(ws + 64 + 16384);
    float* tok_w   = (float*)(ws + 64 + 32768);
    unsigned short* hbuf = (unsigned short*)(ws + 65536);  // 1024 x 5632 bf16 = 11.5 MB

    hipMemsetAsync(counts, 0, 64, stream);
    hipMemsetAsync(out, 0, (size_t)M_TOK * HD * sizeof(float), stream);

    router_kernel<<<dim3(M_TOK), dim3(64), 0, stream>>>(x, wg, counts, tok_idx, tok_k, tok_w);

    gemm1_mfma<<<dim3(ID / 64, M_TOK / 128, NE), dim3(256), 0, stream>>>(
        x, w1, counts, tok_idx, tok_k, hbuf);

    gemm2_mfma<<<dim3(HD / 128, M_TOK / 128, NE * SPLITK), dim3(256), 0, stream>>>(
        hbuf, w2, counts, tok_idx, tok_k, tok_w, out);
}